// Round 2
// baseline (14272.778 us; speedup 1.0000x reference)
//
#include <hip/hip_runtime.h>
#include <hip/hip_bf16.h>
#include <math.h>

#define BB 128
#define TT 256
#define IDIM 64
#define HD 128
#define G4 512
#define OC 100
#define W1 62
#define W2 60
#define W3 58
#define NPX1 (W1*W1)
#define NPX2 (W2*W2)
#define NPX3 (W3*W3)
#define SS NPX3
#define FF (SS + 2*HD)
#define HIDN 1810
#define ANF 64
#define BC 32            // batch chunk for CNN branch

typedef __hip_bfloat16 bf16;

__device__ __forceinline__ float ldf(const float* p) { return *p; }
__device__ __forceinline__ float ldf(const bf16* p)  { return __bfloat162float(*p); }
__device__ __forceinline__ void  stf(float* p, float v) { *p = v; }
__device__ __forceinline__ void  stf(bf16* p, float v)  { *p = __float2bfloat16(v); }

__global__ void zero_kernel(float* o, int n)
{
    int i = blockIdx.x * 256 + threadIdx.x;
    if (i < n) o[i] = 0.f;
}

// ---------------- conv1: [BC,3,64,64] -> relu -> [BC,100,62,62] (bf16 out) ----------------
__global__ __launch_bounds__(256)
void conv1_kernel(const float* __restrict__ x1,
                  const float* __restrict__ w,     // [100,3,3,3]
                  const float* __restrict__ bias,  // [100]
                  bf16* __restrict__ out)          // [BC,100,62,62]
{
    __shared__ float wl[2700];
    __shared__ float bl[OC];
    int tid = threadIdx.x;
    for (int i = tid; i < 2700; i += 256) wl[i] = w[i];
    if (tid < OC) bl[tid] = bias[tid];
    __syncthreads();
    int b  = blockIdx.x;
    int px = blockIdx.y * 256 + tid;
    if (px >= NPX1) return;
    int y = px / W1, x = px % W1;
    float in[3][3][3];
    const float* xb = x1 + (size_t)b * 3 * 64 * 64;
#pragma unroll
    for (int ic = 0; ic < 3; ic++)
#pragma unroll
        for (int r = 0; r < 3; r++)
#pragma unroll
            for (int c = 0; c < 3; c++)
                in[ic][r][c] = xb[(ic * 64 + y + r) * 64 + x + c];
    bf16* ob = out + (size_t)b * OC * NPX1 + px;
    for (int oc = 0; oc < OC; ++oc) {
        float acc = bl[oc];
        const float* wp = &wl[oc * 27];
#pragma unroll
        for (int ic = 0; ic < 3; ic++)
#pragma unroll
            for (int r = 0; r < 3; r++)
#pragma unroll
                for (int c = 0; c < 3; c++)
                    acc = fmaf(in[ic][r][c], wp[ic * 9 + r * 3 + c], acc);
        ob[(size_t)oc * NPX1] = __float2bfloat16(fmaxf(acc, 0.f));
    }
}

// ------------- conv2 (100->100 3x3 VALID + relu), bf16 in/out, fp32 accumulate -------------
#define ICH 10
__global__ __launch_bounds__(256)
void conv2_kernel(const bf16* __restrict__ in,    // [BC,100,iw,iw]
                  const float* __restrict__ w,    // [100,100,3,3]
                  const float* __restrict__ bias, // [100]
                  bf16* __restrict__ out,         // [BC,100,ow,ow]
                  int iw, int ow)
{
    __shared__ __align__(16) float il[ICH * 3 * 64 + 16];
    __shared__ __align__(16) float wl[ICH * 112 * 12];
    int tid = threadIdx.x;
    int b = blockIdx.x;
    int y = blockIdx.y;
    int tx = tid & 15;
    int ocg = tid >> 4;           // oc = ocg*7 + j, j<7 (0..111, mask >=100)
    int x0 = tx * 4;
    bool active = (x0 < ow);
    float acc[7][4];
#pragma unroll
    for (int j = 0; j < 7; j++) {
        int oc = ocg * 7 + j;
        float bv = (oc < OC) ? bias[oc] : 0.f;
#pragma unroll
        for (int p = 0; p < 4; p++) acc[j][p] = bv;
    }
    for (int ic0 = 0; ic0 < OC; ic0 += ICH) {
        for (int idx = tid; idx < ICH * 3 * 64; idx += 256) {
            int icl = idx / 192; int rem = idx - icl * 192;
            int r = rem >> 6; int xx = rem & 63;
            float v = 0.f;
            if (xx < iw) v = __bfloat162float(in[(((size_t)b * OC + ic0 + icl) * iw + (y + r)) * iw + xx]);
            il[idx] = v;
        }
        for (int idx = tid; idx < ICH * 112 * 12; idx += 256) {
            int icl = idx / (112 * 12); int rem = idx - icl * 112 * 12;
            int oc = rem / 12; int k = rem - oc * 12;
            float v = 0.f;
            if (oc < OC && k < 9) v = w[((size_t)oc * OC + ic0 + icl) * 9 + k];
            wl[idx] = v;
        }
        __syncthreads();
        if (active) {
#pragma unroll 2
            for (int icl = 0; icl < ICH; ++icl) {
                float inr[3][8];
#pragma unroll
                for (int r = 0; r < 3; r++) {
                    float4 a = *(const float4*)&il[(icl * 3 + r) * 64 + x0];
                    float4 bq = *(const float4*)&il[(icl * 3 + r) * 64 + x0 + 4];
                    inr[r][0] = a.x; inr[r][1] = a.y; inr[r][2] = a.z; inr[r][3] = a.w;
                    inr[r][4] = bq.x; inr[r][5] = bq.y; inr[r][6] = bq.z; inr[r][7] = bq.w;
                }
#pragma unroll
                for (int j = 0; j < 7; j++) {
                    const float* wp = &wl[(icl * 112 + ocg * 7 + j) * 12];
                    float wr[9];
                    float4 w0 = *(const float4*)&wp[0];
                    float4 w1 = *(const float4*)&wp[4];
                    wr[0] = w0.x; wr[1] = w0.y; wr[2] = w0.z; wr[3] = w0.w;
                    wr[4] = w1.x; wr[5] = w1.y; wr[6] = w1.z; wr[7] = w1.w;
                    wr[8] = wp[8];
#pragma unroll
                    for (int ky = 0; ky < 3; ky++)
#pragma unroll
                        for (int kx = 0; kx < 3; kx++) {
                            float wv = wr[ky * 3 + kx];
#pragma unroll
                            for (int p = 0; p < 4; p++)
                                acc[j][p] = fmaf(inr[ky][p + kx], wv, acc[j][p]);
                        }
                }
            }
        }
        __syncthreads();
    }
    if (!active) return;
#pragma unroll
    for (int j = 0; j < 7; j++) {
        int oc = ocg * 7 + j;
        if (oc >= OC) continue;
        bf16* op = out + (((size_t)b * OC + oc) * ow + y) * ow + x0;
#pragma unroll
        for (int p = 0; p < 4; p++)
            if (x0 + p < ow) op[p] = __float2bfloat16(fmaxf(acc[j][p], 0.f));
    }
}

// ---------------- GEMM: C[M,N] = A[M,K] @ B[N,K]^T (+bias, +relu); A,C typed ----------------
template<typename TA, typename TC, int BM, int BN, int BK, int TM, int TN, int ACT>
__global__ __launch_bounds__((BM / TM) * (BN / TN))
void gemm_tn(const TA* __restrict__ A, int lda,
             const float* __restrict__ Bmat, int ldb,
             const float* __restrict__ bias,
             TC* __restrict__ C, int ldc,
             int M, int N, int K)
{
    constexpr int TX = BN / TN;
    constexpr int TY = BM / TM;
    constexpr int NT = TX * TY;
    __shared__ float As[BK][BM + 1];
    __shared__ float Bs[BK][BN + 1];
    int tid = threadIdx.x;
    int tx = tid % TX, ty = tid / TX;
    int m0 = blockIdx.x * BM, n0 = blockIdx.y * BN;
    float acc[TM][TN] = {};
    for (int k0 = 0; k0 < K; k0 += BK) {
        for (int idx = tid; idx < BM * BK; idx += NT) {
            int i = idx / BK, j = idx % BK;
            int m = m0 + i, k = k0 + j;
            As[j][i] = (m < M && k < K) ? ldf(&A[(size_t)m * lda + k]) : 0.f;
        }
        for (int idx = tid; idx < BN * BK; idx += NT) {
            int i = idx / BK, j = idx % BK;
            int n = n0 + i, k = k0 + j;
            Bs[j][i] = (n < N && k < K) ? Bmat[(size_t)n * ldb + k] : 0.f;
        }
        __syncthreads();
#pragma unroll
        for (int k = 0; k < BK; ++k) {
            float av[TM], bv[TN];
#pragma unroll
            for (int i = 0; i < TM; i++) av[i] = As[k][ty * TM + i];
#pragma unroll
            for (int j = 0; j < TN; j++) bv[j] = Bs[k][tx * TN + j];
#pragma unroll
            for (int i = 0; i < TM; i++)
#pragma unroll
                for (int j = 0; j < TN; j++)
                    acc[i][j] += av[i] * bv[j];
        }
        __syncthreads();
    }
#pragma unroll
    for (int i = 0; i < TM; i++) {
        int m = m0 + ty * TM + i;
        if (m >= M) continue;
#pragma unroll
        for (int j = 0; j < TN; j++) {
            int n = n0 + tx * TN + j;
            if (n >= N) continue;
            float v = acc[i][j] + (bias ? bias[n] : 0.f);
            if (ACT == 1) v = fmaxf(v, 0.f);
            stf(&C[(size_t)m * ldc + n], v);
        }
    }
}

// ---------------- LSTM recurrence: persistent weights in registers ----------------
__global__ __launch_bounds__(512)
void lstm_recur(const bf16* __restrict__ G,    // [B,T,512] x-part + both biases
                const float* __restrict__ Whh, // [512,128]
                bf16* __restrict__ Y,          // [B,T,128] or nullptr
                float* __restrict__ HN,        // [B,256]
                int hoff)
{
    __shared__ __align__(16) float hl[HD];
    __shared__ float ex[G4];
    int g = threadIdx.x;
    int b = blockIdx.x;
    float4 wv[32];
    const float4* wp = (const float4*)(Whh + (size_t)g * HD);
#pragma unroll
    for (int q = 0; q < 32; q++) wv[q] = wp[q];
    float c = 0.f;
    if (g < HD) hl[g] = 0.f;
    __syncthreads();
    const bf16* Gb = G + (size_t)b * TT * G4;
    for (int t = 0; t < TT; ++t) {
        float dot = __bfloat162float(Gb[t * G4 + g]);
#pragma unroll
        for (int q = 0; q < 32; q++) {
            float4 hv = *(const float4*)&hl[q * 4];
            dot = fmaf(wv[q].x, hv.x, dot);
            dot = fmaf(wv[q].y, hv.y, dot);
            dot = fmaf(wv[q].z, hv.z, dot);
            dot = fmaf(wv[q].w, hv.w, dot);
        }
        float tr;
        if (g < 2 * HD || g >= 3 * HD) tr = 1.f / (1.f + __expf(-dot)); // i,f,o
        else tr = tanhf(dot);                                           // g
        ex[g] = tr;
        __syncthreads();
        if (g < HD) {
            float iv = ex[g], fv = ex[HD + g], gv = ex[2 * HD + g], ov = ex[3 * HD + g];
            c = fv * c + iv * gv;
            float nh = ov * tanhf(c);
            hl[g] = nh;
            if (Y) Y[((size_t)b * TT + t) * HD + g] = __float2bfloat16(nh);
            if (t == TT - 1) HN[(size_t)b * 256 + hoff + g] = nh;
        }
        __syncthreads();
    }
}

// ---------------- small helpers ----------------
__global__ void bias_sum(const float* a, const float* b, float* o, int n)
{
    int i = blockIdx.x * 256 + threadIdx.x;
    if (i < n) o[i] = a[i] + b[i];
}

__global__ __launch_bounds__(256)
void attn_logits(const float* __restrict__ T1,  // [BC*OC,64]
                 const float* __restrict__ HB,  // [BC,64] (chunk base, includes attn1_b)
                 const float* __restrict__ a2w, // [64]
                 const float* __restrict__ a2b, // [1]
                 float* __restrict__ LG)        // [BC*OC]
{
    int tid = threadIdx.x;
    int lane = tid & 63;
    int wid = tid >> 6;
    int m = blockIdx.x * 4 + wid;
    int b = m / OC;
    float v = T1[(size_t)m * ANF + lane] + HB[b * ANF + lane];
    v = tanhf(v) * a2w[lane];
#pragma unroll
    for (int off = 32; off > 0; off >>= 1) v += __shfl_down(v, off, 64);
    if (lane == 0) LG[m] = v + a2b[0];
}

__global__ __launch_bounds__(128)
void softmax100(const float* __restrict__ LG, float* __restrict__ ATT)
{
    __shared__ float red[128];
    int b = blockIdx.x, c = threadIdx.x;
    float v = (c < OC) ? LG[b * OC + c] : -1e30f;
    red[c] = v; __syncthreads();
    for (int s = 64; s > 0; s >>= 1) { if (c < s) red[c] = fmaxf(red[c], red[c + s]); __syncthreads(); }
    float mx = red[0]; __syncthreads();
    float e = (c < OC) ? __expf(v - mx) : 0.f;
    red[c] = e; __syncthreads();
    for (int s = 64; s > 0; s >>= 1) { if (c < s) red[c] += red[c + s]; __syncthreads(); }
    float inv = 1.f / red[0];
    if (c < OC) ATT[b * OC + c] = e * inv;
}

__global__ __launch_bounds__(256)
void ctx_concat(const bf16* __restrict__ XD,   // [BC,100,3364]
                const float* __restrict__ ATT, // [BC,100]
                const float* __restrict__ HN,  // [BC,256] (chunk base)
                float* __restrict__ M)         // [BC,3620] (chunk base)
{
    __shared__ float al[OC];
    int b = blockIdx.x;
    int tid = threadIdx.x;
    if (tid < OC) al[tid] = ATT[b * OC + tid];
    __syncthreads();
    int s = blockIdx.y * 256 + tid;
    if (s < SS) {
        const bf16* xp = XD + (size_t)b * OC * SS + s;
        float acc = 0.f;
#pragma unroll 4
        for (int c = 0; c < OC; c++) acc = fmaf(__bfloat162float(xp[(size_t)c * SS]), al[c], acc);
        M[(size_t)b * FF + s] = acc;
    } else if (s < FF) {
        M[(size_t)b * FF + s] = HN[b * 256 + (s - SS)];
    }
}

__global__ __launch_bounds__(256)
void fc2_kernel(const float* __restrict__ H1, // [128,1810]
                const float* __restrict__ w,  // [1810]
                const float* __restrict__ bias,
                float* __restrict__ out)      // [128]
{
    int tid = threadIdx.x;
    int lane = tid & 63, wid = tid >> 6;
    int b = blockIdx.x * 4 + wid;
    float acc = 0.f;
    for (int j = lane; j < HIDN; j += 64) acc = fmaf(H1[(size_t)b * HIDN + j], w[j], acc);
#pragma unroll
    for (int off = 32; off > 0; off >>= 1) acc += __shfl_down(acc, off, 64);
    if (lane == 0) out[b] = acc + bias[0];
}

extern "C" void kernel_launch(void* const* d_in, const int* in_sizes, int n_in,
                              void* d_out, int out_size, void* d_ws, size_t ws_size,
                              hipStream_t stream)
{
    const float* x1   = (const float*)d_in[0];
    const float* x2   = (const float*)d_in[1];
    const float* c1w  = (const float*)d_in[2];
    const float* c1b  = (const float*)d_in[3];
    const float* c2aw = (const float*)d_in[4];
    const float* c2ab = (const float*)d_in[5];
    const float* c2bw = (const float*)d_in[6];
    const float* c2bb = (const float*)d_in[7];
    const float* wih0 = (const float*)d_in[8];
    const float* whh0 = (const float*)d_in[9];
    const float* bih0 = (const float*)d_in[10];
    const float* bhh0 = (const float*)d_in[11];
    const float* wih1 = (const float*)d_in[12];
    const float* whh1 = (const float*)d_in[13];
    const float* bih1 = (const float*)d_in[14];
    const float* bhh1 = (const float*)d_in[15];
    const float* a1w  = (const float*)d_in[16];
    const float* a1b  = (const float*)d_in[17];
    const float* a2w  = (const float*)d_in[18];
    const float* a2b  = (const float*)d_in[19];
    const float* f1w  = (const float*)d_in[20];
    const float* f1b  = (const float*)d_in[21];
    const float* f2w  = (const float*)d_in[22];
    const float* f2b  = (const float*)d_in[23];
    float* out = (float*)d_out;

    // ---- workspace layout (arena overlay; all offsets 256B aligned) ----
    char* base = (char*)d_ws;
    // big overlay region: LSTM phase then CNN-chunk phase (sequential on stream)
    bf16* G0  = (bf16*)(base + 0);                 // 128*256*512*2  = 33,554,432 B
    bf16* Y0  = (bf16*)(base + 33554432);          // 128*256*128*2  =  8,388,608 B
    bf16* G1  = G0;                                // reuses G0 (G0 dead after lstm0)
    bf16* A1c = (bf16*)(base + 0);                 // 32*100*3844*2  = 24,601,600 B
    bf16* A2c = (bf16*)(base + 24601600);          // 32*100*3600*2  = 23,040,000 B
    bf16* XDc = A1c;                               // 32*100*3364*2  = 21,529,600 B (fits A1c)
    size_t p = 47641600;                           // end of overlay region
    float* BS0  = (float*)(base + p); p += 2048;
    float* BS1  = (float*)(base + p); p += 2048;
    float* HN   = (float*)(base + p); p += 131072;   // 128*256*4
    float* HB   = (float*)(base + p); p += 32768;    // 128*64*4
    float* T1c  = (float*)(base + p); p += 819200;   // 32*100*64*4
    float* LGc  = (float*)(base + p); p += 12800;    // 32*100*4
    float* ATTc = (float*)(base + p); p += 12800;
    float* MB   = (float*)(base + p); p += 1853440;  // 128*3620*4
    float* H1   = (float*)(base + p); p += 926720;   // 128*1810*4
    if (ws_size < p) {  // ~49.1 MiB required; keep output deterministic if short
        zero_kernel<<<1, 128, 0, stream>>>(out, out_size);
        return;
    }

    // ---- LSTM branch (full batch) ----
    bias_sum<<<2, 256, 0, stream>>>(bih0, bhh0, BS0, G4);
    bias_sum<<<2, 256, 0, stream>>>(bih1, bhh1, BS1, G4);
    gemm_tn<float, bf16, 64, 64, 16, 4, 4, 0><<<dim3(512, 8), 256, 0, stream>>>(
        x2, IDIM, wih0, IDIM, BS0, G0, G4, BB * TT, G4, IDIM);
    lstm_recur<<<BB, 512, 0, stream>>>(G0, whh0, Y0, HN, 0);
    gemm_tn<bf16, bf16, 64, 64, 16, 4, 4, 0><<<dim3(512, 8), 256, 0, stream>>>(
        Y0, HD, wih1, HD, BS1, G1, G4, BB * TT, G4, HD);
    lstm_recur<<<BB, 512, 0, stream>>>(G1, whh1, (bf16*)nullptr, HN, HD);

    // hn-part of attention layer 1 (done once, full batch)
    gemm_tn<float, float, 32, 32, 16, 2, 2, 0><<<dim3(4, 2), 256, 0, stream>>>(
        HN, 256, a1w + SS, FF, a1b, HB, ANF, BB, ANF, 256);

    // ---- CNN branch + attention + ctx, chunked over batch ----
    for (int c0 = 0; c0 < BB; c0 += BC) {
        conv1_kernel<<<dim3(BC, 16), 256, 0, stream>>>(
            x1 + (size_t)c0 * 3 * 64 * 64, c1w, c1b, A1c);
        conv2_kernel<<<dim3(BC, W2), 256, 0, stream>>>(A1c, c2aw, c2ab, A2c, W1, W2);
        conv2_kernel<<<dim3(BC, W3), 256, 0, stream>>>(A2c, c2bw, c2bb, XDc, W2, W3);
        gemm_tn<bf16, float, 64, 64, 16, 4, 4, 0><<<dim3(BC * OC / 64, 1), 256, 0, stream>>>(
            XDc, SS, a1w, FF, nullptr, T1c, ANF, BC * OC, ANF, SS);
        attn_logits<<<BC * OC / 4, 256, 0, stream>>>(T1c, HB + (size_t)c0 * ANF, a2w, a2b, LGc);
        softmax100<<<BC, 128, 0, stream>>>(LGc, ATTc);
        ctx_concat<<<dim3(BC, 15), 256, 0, stream>>>(
            XDc, ATTc, HN + (size_t)c0 * 256, MB + (size_t)c0 * FF);
    }

    // ---- fusion MLP ----
    gemm_tn<float, float, 32, 32, 16, 2, 2, 1><<<dim3(4, (HIDN + 31) / 32), 256, 0, stream>>>(
        MB, FF, f1w, FF, f1b, H1, HIDN, BB, HIDN, FF);
    fc2_kernel<<<BB / 4, 256, 0, stream>>>(H1, f2w, f2b, out);
}

// Round 3
// 4815.923 us; speedup vs baseline: 2.9637x; 2.9637x over previous
//
#include <hip/hip_runtime.h>
#include <hip/hip_bf16.h>
#include <math.h>

#define BB 128
#define TT 256
#define IDIM 64
#define HD 128
#define G4 512
#define OC 100
#define W1 62
#define W2 60
#define W3 58
#define NPX1 (W1*W1)
#define NPX2 (W2*W2)
#define NPX3 (W3*W3)
#define SS NPX3
#define FF (SS + 2*HD)
#define HIDN 1810
#define ANF 64
#define BC 32            // batch chunk for CNN branch

typedef __hip_bfloat16 bf16;
typedef __attribute__((ext_vector_type(8))) short bf16x8;
typedef __attribute__((ext_vector_type(4))) float f32x4;

__device__ __forceinline__ float ldf(const float* p) { return *p; }
__device__ __forceinline__ float ldf(const bf16* p)  { return __bfloat162float(*p); }
__device__ __forceinline__ void  stf(float* p, float v) { *p = v; }
__device__ __forceinline__ void  stf(bf16* p, float v)  { *p = __float2bfloat16(v); }

__global__ void zero_kernel(float* o, int n)
{
    int i = blockIdx.x * 256 + threadIdx.x;
    if (i < n) o[i] = 0.f;
}

// ---------------- conv1: [BC,3,64,64] -> relu -> [BC,100,62,62] (bf16 out) ----------------
__global__ __launch_bounds__(256)
void conv1_kernel(const float* __restrict__ x1,
                  const float* __restrict__ w,     // [100,3,3,3]
                  const float* __restrict__ bias,  // [100]
                  bf16* __restrict__ out)          // [BC,100,62,62]
{
    __shared__ float wl[2700];
    __shared__ float bl[OC];
    int tid = threadIdx.x;
    for (int i = tid; i < 2700; i += 256) wl[i] = w[i];
    if (tid < OC) bl[tid] = bias[tid];
    __syncthreads();
    int b  = blockIdx.x;
    int px = blockIdx.y * 256 + tid;
    if (px >= NPX1) return;
    int y = px / W1, x = px % W1;
    float in[3][3][3];
    const float* xb = x1 + (size_t)b * 3 * 64 * 64;
#pragma unroll
    for (int ic = 0; ic < 3; ic++)
#pragma unroll
        for (int r = 0; r < 3; r++)
#pragma unroll
            for (int c = 0; c < 3; c++)
                in[ic][r][c] = xb[(ic * 64 + y + r) * 64 + x + c];
    bf16* ob = out + (size_t)b * OC * NPX1 + px;
    for (int oc = 0; oc < OC; ++oc) {
        float acc = bl[oc];
        const float* wp = &wl[oc * 27];
#pragma unroll
        for (int ic = 0; ic < 3; ic++)
#pragma unroll
            for (int r = 0; r < 3; r++)
#pragma unroll
                for (int c = 0; c < 3; c++)
                    acc = fmaf(in[ic][r][c], wp[ic * 9 + r * 3 + c], acc);
        ob[(size_t)oc * NPX1] = __float2bfloat16(fmaxf(acc, 0.f));
    }
}

// ---------------- conv2 weight repack: fp32 [oc][ic][3][3] -> bf16 WT[t][s][oc112][i32] ----------------
__global__ __launch_bounds__(256)
void wt_repack(const float* __restrict__ w, bf16* __restrict__ WT)
{
    int idx = blockIdx.x * 256 + threadIdx.x;   // over 9*4*112*32 = 129024
    if (idx >= 129024) return;
    int i  = idx & 31;
    int oc = (idx >> 5) % 112;
    int ts = idx / (112 * 32);   // t*4+s
    int s = ts & 3, t = ts >> 2;
    int ic = s * 32 + i;
    float v = 0.f;
    if (oc < OC && ic < OC) v = w[(oc * OC + ic) * 9 + t];
    WT[idx] = __float2bfloat16(v);
}

// ---------------- conv2 via MFMA implicit GEMM ----------------
// grid (BC, ceil(ow/4)); 256 thr = 4 waves, wave = one output row.
// A = weights (M=oc, from WT, global 16B coalesced), B = input patches (N=px, LDS).
__global__ __launch_bounds__(256, 2)
void conv2_mfma(const bf16* __restrict__ in,   // [BC,100,iw,iw]
                const bf16* __restrict__ WT,   // [9][4][112][32] bf16
                const float* __restrict__ bias,
                bf16* __restrict__ out,        // [BC,100,ow,ow]
                int iw, int ow)
{
    __shared__ bf16 il[32 * 412 + 8];          // [icl][6 rows x 68 cols], plane stride 412
    int tid = threadIdx.x;
    int b = blockIdx.x;
    int y0 = blockIdx.y * 4;
    int wid = tid >> 6;
    int l = tid & 63;
    int h = l >> 4;            // 0..3 (K-quarter / C-row-quarter)
    int l16 = l & 15;
    int yo = y0 + wid;         // this wave's output row

    f32x4 acc[7][4];
#pragma unroll
    for (int f = 0; f < 7; f++) {
#pragma unroll
        for (int r = 0; r < 4; r++) {
            int oc = f * 16 + h * 4 + r;
            float bv = (oc < OC) ? bias[oc] : 0.f;
#pragma unroll
            for (int n = 0; n < 4; n++) acc[f][n][r] = bv;
        }
    }

    const size_t ims = (size_t)iw * iw;
    for (int s = 0; s < 4; ++s) {
        __syncthreads();   // il reuse barrier
        // ---- stage input slice (32 ic x 6 rows x 68 cols, zero-padded), coalesced 4B units ----
        for (int it = 0; it < 26; ++it) {
            int u = tid + it * 256;            // 2-col units: 32*6*34 = 6528
            if (u < 6528) {
                int icl = u / 204;             // 6*34
                int rem = u - icl * 204;
                int r = rem / 34;
                int c0 = (rem - r * 34) * 2;
                int ic = s * 32 + icl;
                int yy = y0 + r;
                unsigned int val = 0;
                if (ic < OC && yy < iw && c0 < iw)  // iw even, c0 even => c0+1 < iw
                    val = *(const unsigned int*)(in + (size_t)(b * OC + ic) * ims + (size_t)yy * iw + c0);
                *(unsigned int*)(&il[icl * 412 + r * 68 + c0]) = val;
            }
        }
        __syncthreads();

        // ---- 9 taps ----
        const bf16* wts = WT + (size_t)s * 112 * 32;
#pragma unroll
        for (int ky = 0; ky < 3; ++ky) {
#pragma unroll
            for (int kx = 0; kx < 3; ++kx) {
                int t = ky * 3 + kx;
                // A-fragments: 7 x 16B coalesced global loads (L2-hot)
                uint4 a[7];
                const uint4* wp = (const uint4*)(wts + (size_t)t * 4 * 112 * 32);
#pragma unroll
                for (int f = 0; f < 7; f++)
                    a[f] = wp[(f * 16 + l16) * 4 + h];
                // B-fragments from LDS: lane reads 8 consecutive ic at its pixel
                bf16x8 bfr[4];
                int rbase = (wid + ky) * 68 + kx + l16;
#pragma unroll
                for (int n = 0; n < 4; n++) {
#pragma unroll
                    for (int j = 0; j < 8; j++)
                        ((short*)&bfr[n])[j] = *(const short*)&il[(h * 8 + j) * 412 + rbase + n * 16];
                }
#pragma unroll
                for (int f = 0; f < 7; f++)
#pragma unroll
                    for (int n = 0; n < 4; n++)
                        acc[f][n] = __builtin_amdgcn_mfma_f32_16x16x32_bf16(
                            *(const bf16x8*)&a[f], bfr[n], acc[f][n], 0, 0, 0);
            }
        }
    }

    if (yo < ow) {
#pragma unroll
        for (int f = 0; f < 7; f++) {
#pragma unroll
            for (int r = 0; r < 4; r++) {
                int oc = f * 16 + h * 4 + r;
                if (oc < OC) {
#pragma unroll
                    for (int n = 0; n < 4; n++) {
                        int x = n * 16 + l16;
                        if (x < ow)
                            out[((size_t)(b * OC + oc) * ow + yo) * ow + x] =
                                __float2bfloat16(fmaxf(acc[f][n][r], 0.f));
                    }
                }
            }
        }
    }
}

// ---------------- GEMM: C[M,N] = A[M,K] @ B[N,K]^T (+bias, +relu); A,C typed ----------------
template<typename TA, typename TC, int BM, int BN, int BK, int TM, int TN, int ACT>
__global__ __launch_bounds__((BM / TM) * (BN / TN))
void gemm_tn(const TA* __restrict__ A, int lda,
             const float* __restrict__ Bmat, int ldb,
             const float* __restrict__ bias,
             TC* __restrict__ C, int ldc,
             int M, int N, int K)
{
    constexpr int TX = BN / TN;
    constexpr int TY = BM / TM;
    constexpr int NT = TX * TY;
    __shared__ float As[BK][BM + 1];
    __shared__ float Bs[BK][BN + 1];
    int tid = threadIdx.x;
    int tx = tid % TX, ty = tid / TX;
    int m0 = blockIdx.x * BM, n0 = blockIdx.y * BN;
    float acc[TM][TN] = {};
    for (int k0 = 0; k0 < K; k0 += BK) {
        for (int idx = tid; idx < BM * BK; idx += NT) {
            int i = idx / BK, j = idx % BK;
            int m = m0 + i, k = k0 + j;
            As[j][i] = (m < M && k < K) ? ldf(&A[(size_t)m * lda + k]) : 0.f;
        }
        for (int idx = tid; idx < BN * BK; idx += NT) {
            int i = idx / BK, j = idx % BK;
            int n = n0 + i, k = k0 + j;
            Bs[j][i] = (n < N && k < K) ? Bmat[(size_t)n * ldb + k] : 0.f;
        }
        __syncthreads();
#pragma unroll
        for (int k = 0; k < BK; ++k) {
            float av[TM], bv[TN];
#pragma unroll
            for (int i = 0; i < TM; i++) av[i] = As[k][ty * TM + i];
#pragma unroll
            for (int j = 0; j < TN; j++) bv[j] = Bs[k][tx * TN + j];
#pragma unroll
            for (int i = 0; i < TM; i++)
#pragma unroll
                for (int j = 0; j < TN; j++)
                    acc[i][j] += av[i] * bv[j];
        }
        __syncthreads();
    }
#pragma unroll
    for (int i = 0; i < TM; i++) {
        int m = m0 + ty * TM + i;
        if (m >= M) continue;
#pragma unroll
        for (int j = 0; j < TN; j++) {
            int n = n0 + tx * TN + j;
            if (n >= N) continue;
            float v = acc[i][j] + (bias ? bias[n] : 0.f);
            if (ACT == 1) v = fmaxf(v, 0.f);
            stf(&C[(size_t)m * ldc + n], v);
        }
    }
}

// ---------------- LSTM recurrence: persistent weights in registers ----------------
__global__ __launch_bounds__(512)
void lstm_recur(const bf16* __restrict__ G,    // [B,T,512] x-part + both biases
                const float* __restrict__ Whh, // [512,128]
                bf16* __restrict__ Y,          // [B,T,128] or nullptr
                float* __restrict__ HN,        // [B,256]
                int hoff)
{
    __shared__ __align__(16) float hl[HD];
    __shared__ float ex[G4];
    int g = threadIdx.x;
    int b = blockIdx.x;
    float4 wv[32];
    const float4* wp = (const float4*)(Whh + (size_t)g * HD);
#pragma unroll
    for (int q = 0; q < 32; q++) wv[q] = wp[q];
    float c = 0.f;
    if (g < HD) hl[g] = 0.f;
    __syncthreads();
    const bf16* Gb = G + (size_t)b * TT * G4;
    for (int t = 0; t < TT; ++t) {
        float dot = __bfloat162float(Gb[t * G4 + g]);
#pragma unroll
        for (int q = 0; q < 32; q++) {
            float4 hv = *(const float4*)&hl[q * 4];
            dot = fmaf(wv[q].x, hv.x, dot);
            dot = fmaf(wv[q].y, hv.y, dot);
            dot = fmaf(wv[q].z, hv.z, dot);
            dot = fmaf(wv[q].w, hv.w, dot);
        }
        float tr;
        if (g < 2 * HD || g >= 3 * HD) tr = 1.f / (1.f + __expf(-dot)); // i,f,o
        else tr = tanhf(dot);                                           // g
        ex[g] = tr;
        __syncthreads();
        if (g < HD) {
            float iv = ex[g], fv = ex[HD + g], gv = ex[2 * HD + g], ov = ex[3 * HD + g];
            c = fv * c + iv * gv;
            float nh = ov * tanhf(c);
            hl[g] = nh;
            if (Y) Y[((size_t)b * TT + t) * HD + g] = __float2bfloat16(nh);
            if (t == TT - 1) HN[(size_t)b * 256 + hoff + g] = nh;
        }
        __syncthreads();
    }
}

// ---------------- small helpers ----------------
__global__ void bias_sum(const float* a, const float* b, float* o, int n)
{
    int i = blockIdx.x * 256 + threadIdx.x;
    if (i < n) o[i] = a[i] + b[i];
}

__global__ __launch_bounds__(256)
void attn_logits(const float* __restrict__ T1,  // [BC*OC,64]
                 const float* __restrict__ HB,  // [BC,64] (chunk base, includes attn1_b)
                 const float* __restrict__ a2w, // [64]
                 const float* __restrict__ a2b, // [1]
                 float* __restrict__ LG)        // [BC*OC]
{
    int tid = threadIdx.x;
    int lane = tid & 63;
    int wid = tid >> 6;
    int m = blockIdx.x * 4 + wid;
    int b = m / OC;
    float v = T1[(size_t)m * ANF + lane] + HB[b * ANF + lane];
    v = tanhf(v) * a2w[lane];
#pragma unroll
    for (int off = 32; off > 0; off >>= 1) v += __shfl_down(v, off, 64);
    if (lane == 0) LG[m] = v + a2b[0];
}

__global__ __launch_bounds__(128)
void softmax100(const float* __restrict__ LG, float* __restrict__ ATT)
{
    __shared__ float red[128];
    int b = blockIdx.x, c = threadIdx.x;
    float v = (c < OC) ? LG[b * OC + c] : -1e30f;
    red[c] = v; __syncthreads();
    for (int s = 64; s > 0; s >>= 1) { if (c < s) red[c] = fmaxf(red[c], red[c + s]); __syncthreads(); }
    float mx = red[0]; __syncthreads();
    float e = (c < OC) ? __expf(v - mx) : 0.f;
    red[c] = e; __syncthreads();
    for (int s = 64; s > 0; s >>= 1) { if (c < s) red[c] += red[c + s]; __syncthreads(); }
    float inv = 1.f / red[0];
    if (c < OC) ATT[b * OC + c] = e * inv;
}

__global__ __launch_bounds__(256)
void ctx_concat(const bf16* __restrict__ XD,   // [BC,100,3364]
                const float* __restrict__ ATT, // [BC,100]
                const float* __restrict__ HN,  // [BC,256] (chunk base)
                float* __restrict__ M)         // [BC,3620] (chunk base)
{
    __shared__ float al[OC];
    int b = blockIdx.x;
    int tid = threadIdx.x;
    if (tid < OC) al[tid] = ATT[b * OC + tid];
    __syncthreads();
    int s = blockIdx.y * 256 + tid;
    if (s < SS) {
        const bf16* xp = XD + (size_t)b * OC * SS + s;
        float acc = 0.f;
#pragma unroll 4
        for (int c = 0; c < OC; c++) acc = fmaf(__bfloat162float(xp[(size_t)c * SS]), al[c], acc);
        M[(size_t)b * FF + s] = acc;
    } else if (s < FF) {
        M[(size_t)b * FF + s] = HN[b * 256 + (s - SS)];
    }
}

__global__ __launch_bounds__(256)
void fc2_kernel(const float* __restrict__ H1, // [128,1810]
                const float* __restrict__ w,  // [1810]
                const float* __restrict__ bias,
                float* __restrict__ out)      // [128]
{
    int tid = threadIdx.x;
    int lane = tid & 63, wid = tid >> 6;
    int b = blockIdx.x * 4 + wid;
    float acc = 0.f;
    for (int j = lane; j < HIDN; j += 64) acc = fmaf(H1[(size_t)b * HIDN + j], w[j], acc);
#pragma unroll
    for (int off = 32; off > 0; off >>= 1) acc += __shfl_down(acc, off, 64);
    if (lane == 0) out[b] = acc + bias[0];
}

extern "C" void kernel_launch(void* const* d_in, const int* in_sizes, int n_in,
                              void* d_out, int out_size, void* d_ws, size_t ws_size,
                              hipStream_t stream)
{
    const float* x1   = (const float*)d_in[0];
    const float* x2   = (const float*)d_in[1];
    const float* c1w  = (const float*)d_in[2];
    const float* c1b  = (const float*)d_in[3];
    const float* c2aw = (const float*)d_in[4];
    const float* c2ab = (const float*)d_in[5];
    const float* c2bw = (const float*)d_in[6];
    const float* c2bb = (const float*)d_in[7];
    const float* wih0 = (const float*)d_in[8];
    const float* whh0 = (const float*)d_in[9];
    const float* bih0 = (const float*)d_in[10];
    const float* bhh0 = (const float*)d_in[11];
    const float* wih1 = (const float*)d_in[12];
    const float* whh1 = (const float*)d_in[13];
    const float* bih1 = (const float*)d_in[14];
    const float* bhh1 = (const float*)d_in[15];
    const float* a1w  = (const float*)d_in[16];
    const float* a1b  = (const float*)d_in[17];
    const float* a2w  = (const float*)d_in[18];
    const float* a2b  = (const float*)d_in[19];
    const float* f1w  = (const float*)d_in[20];
    const float* f1b  = (const float*)d_in[21];
    const float* f2w  = (const float*)d_in[22];
    const float* f2b  = (const float*)d_in[23];
    float* out = (float*)d_out;

    // ---- workspace layout (arena overlay; all offsets 256B aligned) ----
    char* base = (char*)d_ws;
    bf16* G0  = (bf16*)(base + 0);                 // 128*256*512*2  = 33,554,432 B
    bf16* Y0  = (bf16*)(base + 33554432);          // 128*256*128*2  =  8,388,608 B
    bf16* G1  = G0;                                // reuses G0
    bf16* A1c = (bf16*)(base + 0);                 // 32*100*3844*2  = 24,601,600 B
    bf16* A2c = (bf16*)(base + 24601600);          // 32*100*3600*2  = 23,040,000 B
    bf16* XDc = A1c;                               // 32*100*3364*2 fits A1c
    size_t p = 47641600;
    float* BS0  = (float*)(base + p); p += 2048;
    float* BS1  = (float*)(base + p); p += 2048;
    float* HN   = (float*)(base + p); p += 131072;   // 128*256*4
    float* HB   = (float*)(base + p); p += 32768;    // 128*64*4
    float* T1c  = (float*)(base + p); p += 819200;   // 32*100*64*4
    float* LGc  = (float*)(base + p); p += 12800;
    float* ATTc = (float*)(base + p); p += 12800;
    float* MB   = (float*)(base + p); p += 1853440;  // 128*3620*4
    float* H1   = (float*)(base + p); p += 926720;   // 128*1810*4
    bf16* WTa   = (bf16*)(base + p); p += 258048;    // 9*4*112*32*2
    bf16* WTb   = (bf16*)(base + p); p += 258048;
    if (ws_size < p) {  // ~49.5 MiB required; keep output deterministic if short
        zero_kernel<<<1, 128, 0, stream>>>(out, out_size);
        return;
    }

    // ---- one-time (per launch) conv2 weight repack to MFMA-ready bf16 ----
    wt_repack<<<504, 256, 0, stream>>>(c2aw, WTa);
    wt_repack<<<504, 256, 0, stream>>>(c2bw, WTb);

    // ---- LSTM branch (full batch) ----
    bias_sum<<<2, 256, 0, stream>>>(bih0, bhh0, BS0, G4);
    bias_sum<<<2, 256, 0, stream>>>(bih1, bhh1, BS1, G4);
    gemm_tn<float, bf16, 64, 64, 16, 4, 4, 0><<<dim3(512, 8), 256, 0, stream>>>(
        x2, IDIM, wih0, IDIM, BS0, G0, G4, BB * TT, G4, IDIM);
    lstm_recur<<<BB, 512, 0, stream>>>(G0, whh0, Y0, HN, 0);
    gemm_tn<bf16, bf16, 64, 64, 16, 4, 4, 0><<<dim3(512, 8), 256, 0, stream>>>(
        Y0, HD, wih1, HD, BS1, G1, G4, BB * TT, G4, HD);
    lstm_recur<<<BB, 512, 0, stream>>>(G1, whh1, (bf16*)nullptr, HN, HD);

    // hn-part of attention layer 1 (full batch, once)
    gemm_tn<float, float, 32, 32, 16, 2, 2, 0><<<dim3(4, 2), 256, 0, stream>>>(
        HN, 256, a1w + SS, FF, a1b, HB, ANF, BB, ANF, 256);

    // ---- CNN branch + attention + ctx, chunked over batch ----
    for (int c0 = 0; c0 < BB; c0 += BC) {
        conv1_kernel<<<dim3(BC, 16), 256, 0, stream>>>(
            x1 + (size_t)c0 * 3 * 64 * 64, c1w, c1b, A1c);
        conv2_mfma<<<dim3(BC, 15), 256, 0, stream>>>(A1c, WTa, c2ab, A2c, W1, W2);
        conv2_mfma<<<dim3(BC, 15), 256, 0, stream>>>(A2c, WTb, c2bb, XDc, W2, W3);
        gemm_tn<bf16, float, 64, 64, 16, 4, 4, 0><<<dim3(BC * OC / 64, 1), 256, 0, stream>>>(
            XDc, SS, a1w, FF, nullptr, T1c, ANF, BC * OC, ANF, SS);
        attn_logits<<<BC * OC / 4, 256, 0, stream>>>(T1c, HB + (size_t)c0 * ANF, a2w, a2b, LGc);
        softmax100<<<BC, 128, 0, stream>>>(LGc, ATTc);
        ctx_concat<<<dim3(BC, 15), 256, 0, stream>>>(
            XDc, ATTc, HN + (size_t)c0 * 256, MB + (size_t)c0 * FF);
    }

    // ---- fusion MLP ----
    gemm_tn<float, float, 32, 32, 16, 2, 2, 1><<<dim3(4, (HIDN + 31) / 32), 256, 0, stream>>>(
        MB, FF, f1w, FF, f1b, H1, HIDN, BB, HIDN, FF);
    fc2_kernel<<<BB / 4, 256, 0, stream>>>(H1, f2w, f2b, out);
}

// Round 4
// 2037.377 us; speedup vs baseline: 7.0055x; 2.3638x over previous
//
#include <hip/hip_runtime.h>
#include <hip/hip_bf16.h>
#include <math.h>

#define BB 128
#define TT 256
#define IDIM 64
#define HD 128
#define G4 512
#define OC 100
#define W1 62
#define W2 60
#define W3 58
#define NPX1 (W1*W1)
#define NPX2 (W2*W2)
#define NPX3 (W3*W3)
#define SS NPX3
#define FF (SS + 2*HD)
#define HIDN 1810
#define ANF 64
#define BC 32            // batch chunk for CNN branch

typedef __hip_bfloat16 bf16;
typedef __attribute__((ext_vector_type(8))) short bf16x8;
typedef __attribute__((ext_vector_type(4))) short bf16x4;
typedef __attribute__((ext_vector_type(4))) float f32x4;

__device__ __forceinline__ float ldf(const float* p) { return *p; }
__device__ __forceinline__ float ldf(const bf16* p)  { return __bfloat162float(*p); }
__device__ __forceinline__ void  stf(float* p, float v) { *p = v; }
__device__ __forceinline__ void  stf(bf16* p, float v)  { *p = __float2bfloat16(v); }

__global__ void zero_kernel(float* o, int n)
{
    int i = blockIdx.x * 256 + threadIdx.x;
    if (i < n) o[i] = 0.f;
}

// ---------------- fp32 -> bf16 vectorized convert ----------------
__global__ __launch_bounds__(256)
void cvt4_bf16(const float* __restrict__ s, bf16* __restrict__ d, int n4)
{
    int i = blockIdx.x * 256 + threadIdx.x;
    if (i >= n4) return;
    float4 v = ((const float4*)s)[i];
    bf16x4 o;
    bf16 t;
    t = __float2bfloat16(v.x); ((short*)&o)[0] = *(short*)&t;
    t = __float2bfloat16(v.y); ((short*)&o)[1] = *(short*)&t;
    t = __float2bfloat16(v.z); ((short*)&o)[2] = *(short*)&t;
    t = __float2bfloat16(v.w); ((short*)&o)[3] = *(short*)&t;
    *(bf16x4*)(d + 4 * (size_t)i) = o;
}

// ---------------- conv1: [BC,3,64,64] -> relu -> [BC,100,62,62] (bf16 out) ----------------
__global__ __launch_bounds__(256)
void conv1_kernel(const float* __restrict__ x1,
                  const float* __restrict__ w,     // [100,3,3,3]
                  const float* __restrict__ bias,  // [100]
                  bf16* __restrict__ out)          // [BC,100,62,62]
{
    __shared__ float wl[2700];
    __shared__ float bl[OC];
    int tid = threadIdx.x;
    for (int i = tid; i < 2700; i += 256) wl[i] = w[i];
    if (tid < OC) bl[tid] = bias[tid];
    __syncthreads();
    int b  = blockIdx.x;
    int px = blockIdx.y * 256 + tid;
    if (px >= NPX1) return;
    int y = px / W1, x = px % W1;
    float in[3][3][3];
    const float* xb = x1 + (size_t)b * 3 * 64 * 64;
#pragma unroll
    for (int ic = 0; ic < 3; ic++)
#pragma unroll
        for (int r = 0; r < 3; r++)
#pragma unroll
            for (int c = 0; c < 3; c++)
                in[ic][r][c] = xb[(ic * 64 + y + r) * 64 + x + c];
    bf16* ob = out + (size_t)b * OC * NPX1 + px;
    for (int oc = 0; oc < OC; ++oc) {
        float acc = bl[oc];
        const float* wp = &wl[oc * 27];
#pragma unroll
        for (int ic = 0; ic < 3; ic++)
#pragma unroll
            for (int r = 0; r < 3; r++)
#pragma unroll
                for (int c = 0; c < 3; c++)
                    acc = fmaf(in[ic][r][c], wp[ic * 9 + r * 3 + c], acc);
        ob[(size_t)oc * NPX1] = __float2bfloat16(fmaxf(acc, 0.f));
    }
}

// ---------------- conv2 weight repack: fp32 [oc][ic][3][3] -> bf16 WT[t][s][oc112][i32] ----------------
__global__ __launch_bounds__(256)
void wt_repack(const float* __restrict__ w, bf16* __restrict__ WT)
{
    int idx = blockIdx.x * 256 + threadIdx.x;   // over 9*4*112*32 = 129024
    if (idx >= 129024) return;
    int i  = idx & 31;
    int oc = (idx >> 5) % 112;
    int ts = idx / (112 * 32);   // t*4+s
    int s = ts & 3, t = ts >> 2;
    int ic = s * 32 + i;
    float v = 0.f;
    if (oc < OC && ic < OC) v = w[(oc * OC + ic) * 9 + t];
    WT[idx] = __float2bfloat16(v);
}

// ---------------- conv2 via MFMA implicit GEMM ----------------
__global__ __launch_bounds__(256, 2)
void conv2_mfma(const bf16* __restrict__ in,   // [BC,100,iw,iw]
                const bf16* __restrict__ WT,   // [9][4][112][32] bf16
                const float* __restrict__ bias,
                bf16* __restrict__ out,        // [BC,100,ow,ow]
                int iw, int ow)
{
    __shared__ bf16 il[32 * 412 + 8];          // [icl][6 rows x 68 cols], plane stride 412
    int tid = threadIdx.x;
    int b = blockIdx.x;
    int y0 = blockIdx.y * 4;
    int wid = tid >> 6;
    int l = tid & 63;
    int h = l >> 4;
    int l16 = l & 15;
    int yo = y0 + wid;

    f32x4 acc[7][4];
#pragma unroll
    for (int f = 0; f < 7; f++) {
#pragma unroll
        for (int r = 0; r < 4; r++) {
            int oc = f * 16 + h * 4 + r;
            float bv = (oc < OC) ? bias[oc] : 0.f;
#pragma unroll
            for (int n = 0; n < 4; n++) acc[f][n][r] = bv;
        }
    }

    const size_t ims = (size_t)iw * iw;
    for (int s = 0; s < 4; ++s) {
        __syncthreads();
        for (int it = 0; it < 26; ++it) {
            int u = tid + it * 256;            // 2-col units: 32*6*34 = 6528
            if (u < 6528) {
                int icl = u / 204;
                int rem = u - icl * 204;
                int r = rem / 34;
                int c0 = (rem - r * 34) * 2;
                int ic = s * 32 + icl;
                int yy = y0 + r;
                unsigned int val = 0;
                if (ic < OC && yy < iw && c0 < iw)
                    val = *(const unsigned int*)(in + (size_t)(b * OC + ic) * ims + (size_t)yy * iw + c0);
                *(unsigned int*)(&il[icl * 412 + r * 68 + c0]) = val;
            }
        }
        __syncthreads();

        const bf16* wts = WT + (size_t)s * 112 * 32;
#pragma unroll
        for (int ky = 0; ky < 3; ++ky) {
#pragma unroll
            for (int kx = 0; kx < 3; ++kx) {
                int t = ky * 3 + kx;
                uint4 a[7];
                const uint4* wp = (const uint4*)(wts + (size_t)t * 4 * 112 * 32);
#pragma unroll
                for (int f = 0; f < 7; f++)
                    a[f] = wp[(f * 16 + l16) * 4 + h];
                bf16x8 bfr[4];
                int rbase = (wid + ky) * 68 + kx + l16;
#pragma unroll
                for (int n = 0; n < 4; n++) {
#pragma unroll
                    for (int j = 0; j < 8; j++)
                        ((short*)&bfr[n])[j] = *(const short*)&il[(h * 8 + j) * 412 + rbase + n * 16];
                }
#pragma unroll
                for (int f = 0; f < 7; f++)
#pragma unroll
                    for (int n = 0; n < 4; n++)
                        acc[f][n] = __builtin_amdgcn_mfma_f32_16x16x32_bf16(
                            *(const bf16x8*)&a[f], bfr[n], acc[f][n], 0, 0, 0);
            }
        }
    }

    if (yo < ow) {
#pragma unroll
        for (int f = 0; f < 7; f++) {
#pragma unroll
            for (int r = 0; r < 4; r++) {
                int oc = f * 16 + h * 4 + r;
                if (oc < OC) {
#pragma unroll
                    for (int n = 0; n < 4; n++) {
                        int x = n * 16 + l16;
                        if (x < ow)
                            out[((size_t)(b * OC + oc) * ow + yo) * ow + x] =
                                __float2bfloat16(fmaxf(acc[f][n][r], 0.f));
                    }
                }
            }
        }
    }
}

// ---------------- generic bf16 MFMA GEMM: C[M,N] = A[M,K] @ B[N,K]^T (+bias, +relu) ----------------
// 64x64x64 tile, 4 waves (wave w owns rows w*16..w*16+15), fp32 accum.
template<typename TC, int ACT>
__global__ __launch_bounds__(256)
void gemm_mfma(const bf16* __restrict__ A, int lda,
               const bf16* __restrict__ B, int ldb,
               const float* __restrict__ bias,
               TC* __restrict__ C, int ldc,
               int M, int N, int K)
{
    __shared__ bf16 As[64 * 72];
    __shared__ bf16 Bs[64 * 72];
    int tid = threadIdx.x;
    int l = tid & 63, wid = tid >> 6;
    int l16 = l & 15, h = l >> 4;
    int m0 = blockIdx.x * 64, n0 = blockIdx.y * 64;
    f32x4 acc[4];
#pragma unroll
    for (int nb = 0; nb < 4; nb++) acc[nb] = (f32x4){0.f, 0.f, 0.f, 0.f};

    int rs = tid >> 3;             // 0..31 staging row
    int kc = (tid & 7) * 8;        // 0..56 staging k-col

    for (int k0 = 0; k0 < K; k0 += 64) {
        int kr = K - k0;
#pragma unroll
        for (int half = 0; half < 2; half++) {
            int rr = rs + half * 32;
            bf16x8 av = {0, 0, 0, 0, 0, 0, 0, 0};
            int m = m0 + rr;
            if (m < M) {
                const short* src = (const short*)(A + (size_t)m * lda + k0 + kc);
                if (kc + 8 <= kr) av = *(const bf16x8*)src;
                else if (kc < kr) {
                    for (int j = 0; j < 8; j++) if (kc + j < kr) ((short*)&av)[j] = src[j];
                }
            }
            *(bf16x8*)&As[rr * 72 + kc] = av;
            bf16x8 bv = {0, 0, 0, 0, 0, 0, 0, 0};
            int n = n0 + rr;
            if (n < N) {
                const short* src = (const short*)(B + (size_t)n * ldb + k0 + kc);
                if (kc + 8 <= kr) bv = *(const bf16x8*)src;
                else if (kc < kr) {
                    for (int j = 0; j < 8; j++) if (kc + j < kr) ((short*)&bv)[j] = src[j];
                }
            }
            *(bf16x8*)&Bs[rr * 72 + kc] = bv;
        }
        __syncthreads();
#pragma unroll
        for (int kk = 0; kk < 2; kk++) {
            bf16x8 af = *(const bf16x8*)&As[(wid * 16 + l16) * 72 + kk * 32 + h * 8];
#pragma unroll
            for (int nb = 0; nb < 4; nb++) {
                bf16x8 bfr = *(const bf16x8*)&Bs[(nb * 16 + l16) * 72 + kk * 32 + h * 8];
                acc[nb] = __builtin_amdgcn_mfma_f32_16x16x32_bf16(af, bfr, acc[nb], 0, 0, 0);
            }
        }
        __syncthreads();
    }
#pragma unroll
    for (int nb = 0; nb < 4; nb++) {
        int col = n0 + nb * 16 + l16;
        if (col >= N) continue;
        float bv = bias ? bias[col] : 0.f;
#pragma unroll
        for (int reg = 0; reg < 4; reg++) {
            int row = m0 + wid * 16 + h * 4 + reg;
            if (row < M) {
                float v = acc[nb][reg] + bv;
                if (ACT == 1) v = fmaxf(v, 0.f);
                stf(&C[(size_t)row * ldc + col], v);
            }
        }
    }
}

// ---------------- small fp32 GEMM (kept for tiny HB matmul) ----------------
template<typename TA, typename TC, int BM, int BN, int BK, int TM, int TN, int ACT>
__global__ __launch_bounds__((BM / TM) * (BN / TN))
void gemm_tn(const TA* __restrict__ A, int lda,
             const float* __restrict__ Bmat, int ldb,
             const float* __restrict__ bias,
             TC* __restrict__ C, int ldc,
             int M, int N, int K)
{
    constexpr int TX = BN / TN;
    constexpr int TY = BM / TM;
    constexpr int NT = TX * TY;
    __shared__ float As[BK][BM + 1];
    __shared__ float Bs[BK][BN + 1];
    int tid = threadIdx.x;
    int tx = tid % TX, ty = tid / TX;
    int m0 = blockIdx.x * BM, n0 = blockIdx.y * BN;
    float acc[TM][TN] = {};
    for (int k0 = 0; k0 < K; k0 += BK) {
        for (int idx = tid; idx < BM * BK; idx += NT) {
            int i = idx / BK, j = idx % BK;
            int m = m0 + i, k = k0 + j;
            As[j][i] = (m < M && k < K) ? ldf(&A[(size_t)m * lda + k]) : 0.f;
        }
        for (int idx = tid; idx < BN * BK; idx += NT) {
            int i = idx / BK, j = idx % BK;
            int n = n0 + i, k = k0 + j;
            Bs[j][i] = (n < N && k < K) ? Bmat[(size_t)n * ldb + k] : 0.f;
        }
        __syncthreads();
#pragma unroll
        for (int k = 0; k < BK; ++k) {
            float av[TM], bv[TN];
#pragma unroll
            for (int i = 0; i < TM; i++) av[i] = As[k][ty * TM + i];
#pragma unroll
            for (int j = 0; j < TN; j++) bv[j] = Bs[k][tx * TN + j];
#pragma unroll
            for (int i = 0; i < TM; i++)
#pragma unroll
                for (int j = 0; j < TN; j++)
                    acc[i][j] += av[i] * bv[j];
        }
        __syncthreads();
    }
#pragma unroll
    for (int i = 0; i < TM; i++) {
        int m = m0 + ty * TM + i;
        if (m >= M) continue;
#pragma unroll
        for (int j = 0; j < TN; j++) {
            int n = n0 + tx * TN + j;
            if (n >= N) continue;
            float v = acc[i][j] + (bias ? bias[n] : 0.f);
            if (ACT == 1) v = fmaxf(v, 0.f);
            stf(&C[(size_t)m * ldc + n], v);
        }
    }
}

// ---------------- LSTM recurrence: persistent weights in registers ----------------
__global__ __launch_bounds__(512)
void lstm_recur(const bf16* __restrict__ G,    // [B,T,512] x-part + both biases
                const float* __restrict__ Whh, // [512,128]
                bf16* __restrict__ Y,          // [B,T,128] or nullptr
                float* __restrict__ HN,        // [B,256]
                int hoff)
{
    __shared__ __align__(16) float hl[HD];
    __shared__ float ex[G4];
    int g = threadIdx.x;
    int b = blockIdx.x;
    float4 wv[32];
    const float4* wp = (const float4*)(Whh + (size_t)g * HD);
#pragma unroll
    for (int q = 0; q < 32; q++) wv[q] = wp[q];
    float c = 0.f;
    if (g < HD) hl[g] = 0.f;
    __syncthreads();
    const bf16* Gb = G + (size_t)b * TT * G4;
    for (int t = 0; t < TT; ++t) {
        float dot = __bfloat162float(Gb[t * G4 + g]);
        float a0 = 0.f, a1 = 0.f, a2 = 0.f, a3 = 0.f;
#pragma unroll
        for (int q = 0; q < 32; q += 4) {
            float4 h0 = *(const float4*)&hl[q * 4];
            float4 h1 = *(const float4*)&hl[q * 4 + 4];
            float4 h2 = *(const float4*)&hl[q * 4 + 8];
            float4 h3 = *(const float4*)&hl[q * 4 + 12];
            a0 = fmaf(wv[q].x, h0.x, a0);   a0 = fmaf(wv[q].y, h0.y, a0);
            a0 = fmaf(wv[q].z, h0.z, a0);   a0 = fmaf(wv[q].w, h0.w, a0);
            a1 = fmaf(wv[q+1].x, h1.x, a1); a1 = fmaf(wv[q+1].y, h1.y, a1);
            a1 = fmaf(wv[q+1].z, h1.z, a1); a1 = fmaf(wv[q+1].w, h1.w, a1);
            a2 = fmaf(wv[q+2].x, h2.x, a2); a2 = fmaf(wv[q+2].y, h2.y, a2);
            a2 = fmaf(wv[q+2].z, h2.z, a2); a2 = fmaf(wv[q+2].w, h2.w, a2);
            a3 = fmaf(wv[q+3].x, h3.x, a3); a3 = fmaf(wv[q+3].y, h3.y, a3);
            a3 = fmaf(wv[q+3].z, h3.z, a3); a3 = fmaf(wv[q+3].w, h3.w, a3);
        }
        dot += (a0 + a1) + (a2 + a3);
        float tr;
        if (g < 2 * HD || g >= 3 * HD) tr = 1.f / (1.f + __expf(-dot)); // i,f,o
        else tr = tanhf(dot);                                           // g
        ex[g] = tr;
        __syncthreads();
        if (g < HD) {
            float iv = ex[g], fv = ex[HD + g], gv = ex[2 * HD + g], ov = ex[3 * HD + g];
            c = fv * c + iv * gv;
            float nh = ov * tanhf(c);
            hl[g] = nh;
            if (Y) Y[((size_t)b * TT + t) * HD + g] = __float2bfloat16(nh);
            if (t == TT - 1) HN[(size_t)b * 256 + hoff + g] = nh;
        }
        __syncthreads();
    }
}

// ---------------- small helpers ----------------
__global__ void bias_sum(const float* a, const float* b, float* o, int n)
{
    int i = blockIdx.x * 256 + threadIdx.x;
    if (i < n) o[i] = a[i] + b[i];
}

__global__ __launch_bounds__(256)
void attn_logits(const float* __restrict__ T1,  // [BC*OC,64]
                 const float* __restrict__ HB,  // [BC,64] (chunk base, includes attn1_b)
                 const float* __restrict__ a2w, // [64]
                 const float* __restrict__ a2b, // [1]
                 float* __restrict__ LG)        // [BC*OC]
{
    int tid = threadIdx.x;
    int lane = tid & 63;
    int wid = tid >> 6;
    int m = blockIdx.x * 4 + wid;
    int b = m / OC;
    float v = T1[(size_t)m * ANF + lane] + HB[b * ANF + lane];
    v = tanhf(v) * a2w[lane];
#pragma unroll
    for (int off = 32; off > 0; off >>= 1) v += __shfl_down(v, off, 64);
    if (lane == 0) LG[m] = v + a2b[0];
}

__global__ __launch_bounds__(128)
void softmax100(const float* __restrict__ LG, float* __restrict__ ATT)
{
    __shared__ float red[128];
    int b = blockIdx.x, c = threadIdx.x;
    float v = (c < OC) ? LG[b * OC + c] : -1e30f;
    red[c] = v; __syncthreads();
    for (int s = 64; s > 0; s >>= 1) { if (c < s) red[c] = fmaxf(red[c], red[c + s]); __syncthreads(); }
    float mx = red[0]; __syncthreads();
    float e = (c < OC) ? __expf(v - mx) : 0.f;
    red[c] = e; __syncthreads();
    for (int s = 64; s > 0; s >>= 1) { if (c < s) red[c] += red[c + s]; __syncthreads(); }
    float inv = 1.f / red[0];
    if (c < OC) ATT[b * OC + c] = e * inv;
}

__global__ __launch_bounds__(256)
void ctx_concat(const bf16* __restrict__ XD,   // [BC,100,3364]
                const float* __restrict__ ATT, // [BC,100]
                const float* __restrict__ HN,  // [BC,256] (chunk base)
                bf16* __restrict__ M)          // [BC,3620] bf16 (chunk base)
{
    __shared__ float al[OC];
    int b = blockIdx.x;
    int tid = threadIdx.x;
    if (tid < OC) al[tid] = ATT[b * OC + tid];
    __syncthreads();
    int s = blockIdx.y * 256 + tid;
    if (s < SS) {
        const bf16* xp = XD + (size_t)b * OC * SS + s;
        float acc = 0.f;
#pragma unroll 4
        for (int c = 0; c < OC; c++) acc = fmaf(__bfloat162float(xp[(size_t)c * SS]), al[c], acc);
        M[(size_t)b * FF + s] = __float2bfloat16(acc);
    } else if (s < FF) {
        M[(size_t)b * FF + s] = __float2bfloat16(HN[b * 256 + (s - SS)]);
    }
}

__global__ __launch_bounds__(256)
void fc2_kernel(const float* __restrict__ H1, // [128,1810]
                const float* __restrict__ w,  // [1810]
                const float* __restrict__ bias,
                float* __restrict__ out)      // [128]
{
    int tid = threadIdx.x;
    int lane = tid & 63, wid = tid >> 6;
    int b = blockIdx.x * 4 + wid;
    float acc = 0.f;
    for (int j = lane; j < HIDN; j += 64) acc = fmaf(H1[(size_t)b * HIDN + j], w[j], acc);
#pragma unroll
    for (int off = 32; off > 0; off >>= 1) acc += __shfl_down(acc, off, 64);
    if (lane == 0) out[b] = acc + bias[0];
}

extern "C" void kernel_launch(void* const* d_in, const int* in_sizes, int n_in,
                              void* d_out, int out_size, void* d_ws, size_t ws_size,
                              hipStream_t stream)
{
    const float* x1   = (const float*)d_in[0];
    const float* x2   = (const float*)d_in[1];
    const float* c1w  = (const float*)d_in[2];
    const float* c1b  = (const float*)d_in[3];
    const float* c2aw = (const float*)d_in[4];
    const float* c2ab = (const float*)d_in[5];
    const float* c2bw = (const float*)d_in[6];
    const float* c2bb = (const float*)d_in[7];
    const float* wih0 = (const float*)d_in[8];
    const float* whh0 = (const float*)d_in[9];
    const float* bih0 = (const float*)d_in[10];
    const float* bhh0 = (const float*)d_in[11];
    const float* wih1 = (const float*)d_in[12];
    const float* whh1 = (const float*)d_in[13];
    const float* bih1 = (const float*)d_in[14];
    const float* bhh1 = (const float*)d_in[15];
    const float* a1w  = (const float*)d_in[16];
    const float* a1b  = (const float*)d_in[17];
    const float* a2w  = (const float*)d_in[18];
    const float* a2b  = (const float*)d_in[19];
    const float* f1w  = (const float*)d_in[20];
    const float* f1b  = (const float*)d_in[21];
    const float* f2w  = (const float*)d_in[22];
    const float* f2b  = (const float*)d_in[23];
    float* out = (float*)d_out;

    // ---- workspace layout (arena with phase overlays; offsets 256B aligned) ----
    char* base = (char*)d_ws;
    // overlay region [0, 47,641,600):
    //  LSTM phase: G0 | Y0 | X2B | WIH0B | WIH1B
    bf16* G0    = (bf16*)(base + 0);            // 33,554,432
    bf16* Y0    = (bf16*)(base + 33554432);     //  8,388,608
    bf16* G1    = G0;                           // reuse
    bf16* X2B   = (bf16*)(base + 41943040);     //  4,194,304 (128*256*64*2)
    bf16* WIH0B = (bf16*)(base + 46137344);     //     65,536
    bf16* WIH1B = (bf16*)(base + 46202880);     //    131,072 (end 46,333,952)
    //  CNN phase: A1c | A2c
    bf16* A1c = (bf16*)(base + 0);              // 24,601,600
    bf16* A2c = (bf16*)(base + 24601600);       // 23,040,000 (end 47,641,600)
    bf16* XDc = A1c;
    //  FC1 phase: F1WB
    bf16* F1WB = (bf16*)(base + 0);             // 13,104,400 (1810*3620*2)
    size_t p = 47641600;
    float* BS0  = (float*)(base + p); p += 2048;
    float* BS1  = (float*)(base + p); p += 2048;
    float* HN   = (float*)(base + p); p += 131072;   // 128*256*4
    float* HB   = (float*)(base + p); p += 32768;    // 128*64*4
    float* T1c  = (float*)(base + p); p += 819200;   // 32*100*64*4
    float* LGc  = (float*)(base + p); p += 12800;
    float* ATTc = (float*)(base + p); p += 12800;
    bf16*  MBb  = (bf16*)(base + p); p += 926720;    // 128*3620*2
    float* H1   = (float*)(base + p); p += 926720;   // 128*1810*4
    bf16* WTa   = (bf16*)(base + p); p += 258048;    // 9*4*112*32*2
    bf16* WTb   = (bf16*)(base + p); p += 258048;
    bf16* A1WB  = (bf16*)(base + p); p += 463360;    // 64*3620*2
    if (ws_size < p) {  // ~49.1 MiB required; keep output deterministic if short
        zero_kernel<<<1, 128, 0, stream>>>(out, out_size);
        return;
    }

    // ---- weight conversions / repacks ----
    wt_repack<<<504, 256, 0, stream>>>(c2aw, WTa);
    wt_repack<<<504, 256, 0, stream>>>(c2bw, WTb);
    cvt4_bf16<<<2048, 256, 0, stream>>>(x2,   X2B,   524288);  // 128*256*64/4
    cvt4_bf16<<<32,   256, 0, stream>>>(wih0, WIH0B, 8192);
    cvt4_bf16<<<64,   256, 0, stream>>>(wih1, WIH1B, 16384);
    cvt4_bf16<<<227,  256, 0, stream>>>(a1w,  A1WB,  57920);   // 64*3620/4
    bias_sum<<<2, 256, 0, stream>>>(bih0, bhh0, BS0, G4);
    bias_sum<<<2, 256, 0, stream>>>(bih1, bhh1, BS1, G4);

    // ---- LSTM branch (full batch) ----
    gemm_mfma<bf16, 0><<<dim3(512, 8), 256, 0, stream>>>(
        X2B, IDIM, WIH0B, IDIM, BS0, G0, G4, BB * TT, G4, IDIM);
    lstm_recur<<<BB, 512, 0, stream>>>(G0, whh0, Y0, HN, 0);
    gemm_mfma<bf16, 0><<<dim3(512, 8), 256, 0, stream>>>(
        Y0, HD, WIH1B, HD, BS1, G1, G4, BB * TT, G4, HD);
    lstm_recur<<<BB, 512, 0, stream>>>(G1, whh1, (bf16*)nullptr, HN, HD);

    // hn-part of attention layer 1 (full batch, once; tiny fp32)
    gemm_tn<float, float, 32, 32, 16, 2, 2, 0><<<dim3(4, 2), 256, 0, stream>>>(
        HN, 256, a1w + SS, FF, a1b, HB, ANF, BB, ANF, 256);

    // ---- CNN branch + attention + ctx, chunked over batch ----
    for (int c0 = 0; c0 < BB; c0 += BC) {
        conv1_kernel<<<dim3(BC, 16), 256, 0, stream>>>(
            x1 + (size_t)c0 * 3 * 64 * 64, c1w, c1b, A1c);
        conv2_mfma<<<dim3(BC, 15), 256, 0, stream>>>(A1c, WTa, c2ab, A2c, W1, W2);
        conv2_mfma<<<dim3(BC, 15), 256, 0, stream>>>(A2c, WTb, c2bb, XDc, W2, W3);
        gemm_mfma<float, 0><<<dim3(50, 1), 256, 0, stream>>>(
            XDc, SS, A1WB, FF, nullptr, T1c, ANF, BC * OC, ANF, SS);
        attn_logits<<<BC * OC / 4, 256, 0, stream>>>(T1c, HB + (size_t)c0 * ANF, a2w, a2b, LGc);
        softmax100<<<BC, 128, 0, stream>>>(LGc, ATTc);
        ctx_concat<<<dim3(BC, 15), 256, 0, stream>>>(
            XDc, ATTc, HN + (size_t)c0 * 256, MBb + (size_t)c0 * FF);
    }

    // ---- fusion MLP ----
    cvt4_bf16<<<6399, 256, 0, stream>>>(f1w, F1WB, 1638050);   // 1810*3620/4
    gemm_mfma<float, 1><<<dim3(2, 29), 256, 0, stream>>>(
        MBb, FF, F1WB, FF, f1b, H1, HIDN, BB, HIDN, FF);
    fc2_kernel<<<BB / 4, 256, 0, stream>>>(H1, f2w, f2b, out);
}